// Round 5
// baseline (203.463 us; speedup 1.0000x reference)
//
#include <hip/hip_runtime.h>

#define N_BINS 100
#define BLOCK 256
#define GRID 2048          // 8 blocks/CU x 4 waves = 32 waves/CU
#define EPS 1e-4f          // boundary uncertainty band; analytic fma error < 3e-5

// ---------- Phase A: classify each element, write u8 bin code to ws ----------
__global__ __launch_bounds__(BLOCK) void bin_kernel(const float* __restrict__ x,
                                                    const float* __restrict__ bounds,
                                                    unsigned char* __restrict__ binout,
                                                    int n) {
    __shared__ float sb[N_BINS + 1];
    const int tid = threadIdx.x;
    if (tid < N_BINS + 1) sb[tid] = bounds[tid];
    __syncthreads();
    const float b0 = sb[0], bN = sb[N_BINS];
    const float scale = (float)N_BINS / (bN - b0);
    const float c0 = -b0 * scale;

    const int n4 = n >> 2;
    const float4* __restrict__ x4 = (const float4*)x;
    uchar4* __restrict__ b4 = (uchar4*)binout;
    const int gstride = GRID * BLOCK;

    for (int i = blockIdx.x * BLOCK + tid; i < n4; i += gstride) {
        float4 v = x4[i];
        float vals[4] = {v.x, v.y, v.z, v.w};
        unsigned char bb[4];
        #pragma unroll
        for (int k = 0; k < 4; ++k) {
            float val = vals[k];
            float f = fmaf(val, scale, c0);
            int g = (int)f;
            float r = f - (float)g;
            if ((r > EPS) & (r < 1.0f - EPS) & (f > 0.0f) & (f < (float)N_BINS)) {
                bb[k] = (unsigned char)g;       // interior: analytic index exact
            } else {
                // near boundary (~0.5%): exact searchsorted(side='left')-1 walk
                g = min(max(g, 0), N_BINS - 1);
                while (g > 0 && val <= sb[g]) --g;
                while (g < N_BINS - 1 && val > sb[g + 1]) ++g;
                bb[k] = (val > b0 && val <= bN) ? (unsigned char)g : (unsigned char)0xFF;
            }
        }
        b4[i] = make_uchar4(bb[0], bb[1], bb[2], bb[3]);
    }
    // scalar tail (n % 4 — zero for this shape, kept for safety)
    for (int t = (n4 << 2) + blockIdx.x * BLOCK + tid; t < n; t += gstride) {
        float val = x[t];
        int g = min(max((int)fmaf(val, scale, c0), 0), N_BINS - 1);
        while (g > 0 && val <= sb[g]) --g;
        while (g < N_BINS - 1 && val > sb[g + 1]) ++g;
        binout[t] = (val > b0 && val <= bN) ? (unsigned char)g : (unsigned char)0xFF;
    }
}

// ---------- Phase B: count u8 bin codes via bank-private LDS atomics ----------
__global__ __launch_bounds__(BLOCK) void count_kernel(const unsigned char* __restrict__ bins,
                                                      float* __restrict__ out, int n) {
    // sh[bin][col], col = lane&31 -> bank = col: 2 lanes/bank per wave64 atomic (free)
    __shared__ unsigned int sh[N_BINS][32];
    const int tid = threadIdx.x;
    const int col = tid & 31;
    for (int i = tid; i < N_BINS * 32; i += BLOCK) ((unsigned int*)sh)[i] = 0u;
    __syncthreads();

    const int n16 = n >> 4;
    const uint4* __restrict__ b16 = (const uint4*)bins;
    const int gstride = GRID * BLOCK;

    for (int i = blockIdx.x * BLOCK + tid; i < n16; i += gstride) {
        uint4 w = b16[i];
        unsigned int ws4[4] = {w.x, w.y, w.z, w.w};
        #pragma unroll
        for (int j = 0; j < 4; ++j) {
            unsigned int u = ws4[j];
            #pragma unroll
            for (int s = 0; s < 4; ++s) {
                unsigned int b = (u >> (8 * s)) & 0xFFu;
                unsigned int g = (b < N_BINS) ? b : 0u;
                unsigned int inc = (b < N_BINS) ? 1u : 0u;
                atomicAdd(&sh[g][col], inc);
            }
        }
    }
    // tail (n % 16 — zero for this shape)
    for (int t = (n16 << 4) + blockIdx.x * BLOCK + tid; t < n; t += gstride) {
        unsigned int b = bins[t];
        if (b < N_BINS) atomicAdd(&sh[b][col], 1u);
    }

    __syncthreads();
    if (tid < N_BINS) {
        unsigned int c = 0;
        #pragma unroll
        for (int j = 0; j < 32; ++j) c += sh[tid][(j + tid) & 31];
        atomicAdd(&out[tid], (float)c);
    }
}

extern "C" void kernel_launch(void* const* d_in, const int* in_sizes, int n_in,
                              void* d_out, int out_size, void* d_ws, size_t ws_size,
                              hipStream_t stream) {
    const float* x = (const float*)d_in[0];
    const float* bounds = (const float*)d_in[1];
    float* out = (float*)d_out;
    unsigned char* binbuf = (unsigned char*)d_ws;   // needs n bytes (~25 MB); ws is ~384 MB
    const int n = in_sizes[0];

    hipMemsetAsync(d_out, 0, out_size * sizeof(float), stream);
    bin_kernel<<<GRID, BLOCK, 0, stream>>>(x, bounds, binbuf, n);
    count_kernel<<<GRID, BLOCK, 0, stream>>>(binbuf, out, n);
}

// Round 6
// 178.150 us; speedup vs baseline: 1.1421x; 1.1421x over previous
//
#include <hip/hip_runtime.h>

#define N_BINS 100
#define BLOCK 256
#define GRID 2048          // 8 blocks/CU x 4 waves = 32 waves/CU (full occupancy)
#define EPS 1e-4f          // boundary uncertainty band in f-units; analytic fma error < 3e-5

__global__ __launch_bounds__(BLOCK, 8) void hist_kernel(const float* __restrict__ x,
                                                        const float* __restrict__ bounds,
                                                        float* __restrict__ out,
                                                        int n) {
    // bank-private: sh[bin][col], col = lane&31 -> bank = col. 2 lanes/bank per
    // wave64 ds_atomic (free per m136); same-address RMW only if lanes l,l+32
    // pick the same bin (p = 0.01).
    __shared__ float sb[N_BINS + 1];
    __shared__ unsigned int sh[N_BINS][32];

    const int tid = threadIdx.x;
    const int col = tid & 31;

    if (tid < N_BINS + 1) sb[tid] = bounds[tid];
    for (int i = tid; i < N_BINS * 32; i += BLOCK) ((unsigned int*)sh)[i] = 0u;
    __syncthreads();

    const float b0 = sb[0], bN = sb[N_BINS];
    const float scale = (float)N_BINS / (bN - b0);
    const float c0 = -b0 * scale;

    // process one float4: fast path is branch-free & clamp-free (gate guarantees
    // EPS < f < N_BINS-EPS and |f - rint(f)| >= EPS for all 4 elements)
    auto proc4 = [&](float4 v) {
        float f0 = fmaf(v.x, scale, c0);
        float f1 = fmaf(v.y, scale, c0);
        float f2 = fmaf(v.z, scale, c0);
        float f3 = fmaf(v.w, scale, c0);
        bool unc = (fabsf(f0 - rintf(f0)) < EPS) | (f0 <= EPS) | (f0 >= (float)N_BINS - EPS) |
                   (fabsf(f1 - rintf(f1)) < EPS) | (f1 <= EPS) | (f1 >= (float)N_BINS - EPS) |
                   (fabsf(f2 - rintf(f2)) < EPS) | (f2 <= EPS) | (f2 >= (float)N_BINS - EPS) |
                   (fabsf(f3 - rintf(f3)) < EPS) | (f3 <= EPS) | (f3 >= (float)N_BINS - EPS);
        if (__any(unc)) {
            // rare (~5% of wave-steps): exact searchsorted(side='left')-1 walk
            float vals[4] = {v.x, v.y, v.z, v.w};
            #pragma unroll
            for (int k = 0; k < 4; ++k) {
                float val = vals[k];
                int g = min(max((int)fmaf(val, scale, c0), 0), N_BINS - 1);
                while (g > 0 && val <= sb[g]) --g;
                while (g < N_BINS - 1 && val > sb[g + 1]) ++g;
                if (val > b0 && val <= bN) atomicAdd(&sh[g][col], 1u);
            }
        } else {
            atomicAdd(&sh[(int)f0][col], 1u);
            atomicAdd(&sh[(int)f1][col], 1u);
            atomicAdd(&sh[(int)f2][col], 1u);
            atomicAdd(&sh[(int)f3][col], 1u);
        }
    };

    const int n4 = n >> 2;
    const float4* __restrict__ x4 = (const float4*)x;
    const int gstride = GRID * BLOCK;              // 524288
    int i = blockIdx.x * BLOCK + tid;

    // main loop: 4 independent float4 loads in flight (4 KB/wave outstanding)
    for (; i + 3 * gstride < n4; i += 4 * gstride) {
        float4 v0 = x4[i];
        float4 v1 = x4[i + gstride];
        float4 v2 = x4[i + 2 * gstride];
        float4 v3 = x4[i + 3 * gstride];
        proc4(v0);
        proc4(v1);
        proc4(v2);
        proc4(v3);
    }
    // leftover strided groups (none for n = 96*512*512, kept for generality)
    for (; i < n4; i += gstride) proc4(x4[i]);

    // scalar tail (n % 4 — zero here, kept for safety)
    for (int t = (n4 << 2) + blockIdx.x * BLOCK + tid; t < n; t += gstride) {
        float val = x[t];
        int g = min(max((int)fmaf(val, scale, c0), 0), N_BINS - 1);
        while (g > 0 && val <= sb[g]) --g;
        while (g < N_BINS - 1 && val > sb[g + 1]) ++g;
        if (val > b0 && val <= bN) atomicAdd(&sh[g][col], 1u);
    }

    __syncthreads();
    // flush: thread t owns bin t; rotated column order keeps banks distinct
    if (tid < N_BINS) {
        unsigned int c = 0;
        #pragma unroll
        for (int j = 0; j < 32; ++j) c += sh[tid][(j + tid) & 31];
        atomicAdd(&out[tid], (float)c);
    }
}

extern "C" void kernel_launch(void* const* d_in, const int* in_sizes, int n_in,
                              void* d_out, int out_size, void* d_ws, size_t ws_size,
                              hipStream_t stream) {
    const float* x = (const float*)d_in[0];
    const float* bounds = (const float*)d_in[1];
    float* out = (float*)d_out;
    const int n = in_sizes[0];

    hipMemsetAsync(d_out, 0, out_size * sizeof(float), stream);
    hist_kernel<<<GRID, BLOCK, 0, stream>>>(x, bounds, out, n);
}